// Round 15
// baseline (595.756 us; speedup 1.0000x reference)
//
#include <hip/hip_runtime.h>
#include <hip/hip_bf16.h>

// Problem constants
#define NP    1024   // polynomials
#define NM    64     // monomials per poly
#define MD_   16
#define D_    512
#define NH    8
#define DH_   64
#define NL    4
#define FF_   2048
#define HID_  1024
#define NK    2048
#define EPS_  1e-5f

typedef __attribute__((ext_vector_type(8))) short short8;
typedef __attribute__((ext_vector_type(4))) float f32x4;

static __device__ __forceinline__ unsigned short f2bf(float f) {
    __hip_bfloat16 h = __float2bfloat16(f);
    return *reinterpret_cast<unsigned short*>(&h);
}
static __device__ __forceinline__ float bf2f(unsigned short u) {
    unsigned int x = ((unsigned int)u) << 16;
    return __uint_as_float(x);
}

// ---------------------------------------------------------------------------
// MEGA conversion kernel (r14): output sentinel fill + all weight converts +
// QKV pack + bias gather + K=64 pads in ONE launch. 17936 blocks.
// ---------------------------------------------------------------------------
__global__ __launch_bounds__(256) void mega_cvt(
    const float* __restrict__ Wphi1, const float* __restrict__ Wphi2,
    const float* __restrict__ Wrho1, const float* __restrict__ Wrho2,
    const float* __restrict__ Wo,    const float* __restrict__ W1,
    const float* __restrict__ W2,
    unsigned short* __restrict__ w_phi1, unsigned short* __restrict__ w_phi2,
    unsigned short* __restrict__ w_rho1, unsigned short* __restrict__ w_rho2,
    unsigned short* __restrict__ w_o,    unsigned short* __restrict__ w_1,
    unsigned short* __restrict__ w_2,
    const float* __restrict__ Wq, const float* __restrict__ Wk,
    const float* __restrict__ Wv, const float* __restrict__ bq,
    const float* __restrict__ bk, const float* __restrict__ bv,
    unsigned short* __restrict__ w_qkv, float* __restrict__ b_qkvc,
    const float* __restrict__ ideal, unsigned short* __restrict__ id_pad,
    const float* __restrict__ Wm,    unsigned short* __restrict__ wm_pad,
    unsigned short* __restrict__ out)
{
    const int b = blockIdx.x, t = threadIdx.x;
    if (b < 512) {
        // output sentinel: 0xFBFF finite under bf16/fp16/fp32 views (r0-3 lesson)
        const long long i = (long long)b * 256 + t;
        const unsigned int pat = 0xFBFFFBFFu;
        uint4 v = {pat, pat, pat, pat};
        *(uint4*)(out + i * 8) = v;
    } else if (b < 12800) {
        const int i = (b - 512) * 256 + t;   // f4 index < 3145728
        const float* src; unsigned short* dst; int l;
        if      (i <  131072) { src = Wphi1; dst = w_phi1; l = i; }
        else if (i <  393216) { src = Wphi2; dst = w_phi2; l = i -  131072; }
        else if (i <  655360) { src = Wrho1; dst = w_rho1; l = i -  393216; }
        else if (i <  786432) { src = Wrho2; dst = w_rho2; l = i -  655360; }
        else if (i < 1048576) { src = Wo;    dst = w_o;    l = i -  786432; }
        else if (i < 2097152) { src = W1;    dst = w_1;    l = i - 1048576; }
        else                  { src = W2;    dst = w_2;    l = i - 2097152; }
        float4 v = *(const float4*)(src + (size_t)l * 4);
        ushort4 o;
        o.x = f2bf(v.x); o.y = f2bf(v.y); o.z = f2bf(v.z); o.w = f2bf(v.w);
        *(ushort4*)(dst + (size_t)l * 4) = o;
    } else if (b < 15872) {
        const int g = (b - 12800) >> 8;      // 0..11
        const int inner = (b - 12800) & 255;
        const int part = g % 3, l = g / 3;
        const float* src  = (part == 0 ? Wq : part == 1 ? Wk : Wv) + (size_t)l * D_ * D_;
        const float* bsrc = (part == 0 ? bq : part == 1 ? bk : bv) + l * D_;
        unsigned short* dst = w_qkv + (size_t)l * 1536 * D_ + (size_t)part * 512 * D_;
        const int i = inner * 256 + t;       // f4 index < 65536
        float4 v = *(const float4*)(src + (size_t)i * 4);
        ushort4 o;
        o.x = f2bf(v.x); o.y = f2bf(v.y); o.z = f2bf(v.z); o.w = f2bf(v.w);
        *(ushort4*)(dst + (size_t)i * 4) = o;
        if (inner == 0) {
            b_qkvc[l * 1536 + part * 512 + t * 2]     = bsrc[t * 2];
            b_qkvc[l * 1536 + part * 512 + t * 2 + 1] = bsrc[t * 2 + 1];
        }
    } else {
        // pad-convert [nrows][16] f32 -> [nrows][64] bf16 (cols 16..63 = 0)
        const float* src; unsigned short* dst; int row;
        if (b < 17920) { src = ideal; dst = id_pad; row = (b - 15872) * 32 + (t >> 3); }
        else           { src = Wm;    dst = wm_pad; row = (b - 17920) * 32 + (t >> 3); }
        const int c8 = (t & 7) * 8;
        ushort4 o0 = {0, 0, 0, 0}, o1 = {0, 0, 0, 0};
        if (c8 < 16) {
            float4 a = *(const float4*)(src + (size_t)row * 16 + c8);
            float4 bb = *(const float4*)(src + (size_t)row * 16 + c8 + 4);
            o0.x = f2bf(a.x);  o0.y = f2bf(a.y);  o0.z = f2bf(a.z);  o0.w = f2bf(a.w);
            o1.x = f2bf(bb.x); o1.y = f2bf(bb.y); o1.z = f2bf(bb.z); o1.w = f2bf(bb.w);
        }
        *(ushort4*)(dst + (size_t)row * 64 + c8) = o0;
        *(ushort4*)(dst + (size_t)row * 64 + c8 + 4) = o1;
    }
}

__global__ __launch_bounds__(256) void cvt_bf16_kernel(
    const float* __restrict__ in, unsigned short* __restrict__ out, int n4)
{
    const int i = blockIdx.x * 256 + threadIdx.x;
    if (i < n4) {
        float4 v = *(const float4*)(in + (size_t)i * 4);
        ushort4 o;
        o.x = f2bf(v.x); o.y = f2bf(v.y); o.z = f2bf(v.z); o.w = f2bf(v.w);
        *(ushort4*)(out + (size_t)i * 4) = o;
    }
}

// ---------------------------------------------------------------------------
// Staging via global_load_lds, pre-swizzled source (G21). Validated round 8.
// ---------------------------------------------------------------------------
template<int ISSUES>
static __device__ __forceinline__ void stage_tile(
    const unsigned short* __restrict__ src, int ld,
    unsigned short* lds, int wave, int lane)
{
    const int rl  = lane >> 3;
    const int sw8 = (((lane & 7) ^ rl) << 3);
#pragma unroll
    for (int i = 0; i < ISSUES; ++i) {
        const int rbase = i * 32 + wave * 8;
        const unsigned short* g = src + (size_t)(rbase + rl) * ld + sw8;
        unsigned short* l = lds + rbase * 64;
        __builtin_amdgcn_global_load_lds(
            (const __attribute__((address_space(1))) void*)g,
            (__attribute__((address_space(3))) void*)l, 16, 0, 0);
    }
}

// ---------------------------------------------------------------------------
// Unified MFMA bf16 NT GEMM. MODE 2: XCD-aligned 1-D decode (r10, FETCH 6x
// cut). TRANSV: QKV V-region writes transposed vT. DBUF (r13): double-
// buffered K-loop. BOTH (r14): f32 + bf16 mirror. NEW (r15): bf16 output
// epilogue is LDS-bounced to 16B/lane coalesced stores — r14 counters showed
// phi1 (2x less compute than phi2, 128MB bf16 out) matching phi2's 165 us:
// write-bound on 64 scalar 2B stores/thread.
// ---------------------------------------------------------------------------
template<int BM, int BN, int MODE, bool OUTF32, bool BIAS, bool RELU, bool POOL,
         bool RESID, bool TRANSV, bool DBUF, bool BOTH>
__global__ __launch_bounds__(256) void mfma_nt(
    const unsigned short* __restrict__ A, long long aBatch, int lda,
    const unsigned short* __restrict__ W, long long bBatch, int ldb,
    const float* __restrict__ bias,
    const float* __restrict__ resid, int ldr,
    void* __restrict__ Cout, long long cBatch, int ldc,
    int K, float alpha, unsigned short* __restrict__ vTout)
{
    constexpr int BK = 64;
    constexpr int MI = BM / 32, NJ = BN / 32;
    __shared__ unsigned short Asl[(DBUF ? 2 : 1) * BM * BK];
    __shared__ unsigned short Bsl[(DBUF ? 2 : 1) * BN * BK];

    const int tid  = threadIdx.x;
    const int wave = tid >> 6, lane = tid & 63;
    const int wm = wave >> 1, wn = wave & 1;
    int row0, col0;
    if (MODE == 2) {
        const int f = blockIdx.x;
        const int lo = f & 7, mid = (f >> 3) & 7, hi = f >> 6;
        row0 = (hi * 8 + lo) * BM;
        col0 = mid * BN;
    } else {
        row0 = blockIdx.y * BM;
        col0 = blockIdx.x * BN;
    }
    const long long bz = blockIdx.z;
    A += bz * aBatch + (size_t)row0 * lda;
    W += bz * bBatch + (size_t)col0 * ldb;

    f32x4 acc[MI][NJ];
#pragma unroll
    for (int i = 0; i < MI; ++i)
#pragma unroll
        for (int j = 0; j < NJ; ++j) acc[i][j] = (f32x4){0.f, 0.f, 0.f, 0.f};

    if (DBUF) {
        stage_tile<MI>(A, lda, Asl, wave, lane);
        stage_tile<NJ>(W, ldb, Bsl, wave, lane);
        __syncthreads();
    }
    int cur = 0;
    for (int k0 = 0; k0 < K; k0 += BK) {
        const unsigned short *Ac, *Bc;
        if (DBUF) {
            if (k0 + BK < K) {
                stage_tile<MI>(A + k0 + BK, lda, Asl + (cur ^ 1) * BM * BK, wave, lane);
                stage_tile<NJ>(W + k0 + BK, ldb, Bsl + (cur ^ 1) * BN * BK, wave, lane);
            }
            Ac = Asl + cur * BM * BK;
            Bc = Bsl + cur * BN * BK;
        } else {
            stage_tile<MI>(A + k0, lda, Asl, wave, lane);
            stage_tile<NJ>(W + k0, ldb, Bsl, wave, lane);
            __syncthreads();
            Ac = Asl; Bc = Bsl;
        }
#pragma unroll
        for (int ks = 0; ks < 2; ++ks) {
            short8 a[MI], b[NJ];
            const int kbase = ks * 64 + (lane >> 4) * 16;
#pragma unroll
            for (int i = 0; i < MI; ++i) {
                const int ra = wm * (BM / 2) + i * 16 + (lane & 15);
                a[i] = *(const short8*)((const char*)Ac + ra * 128 + (kbase ^ ((ra & 7) << 4)));
            }
#pragma unroll
            for (int j = 0; j < NJ; ++j) {
                const int rb = wn * (BN / 2) + j * 16 + (lane & 15);
                b[j] = *(const short8*)((const char*)Bc + rb * 128 + (kbase ^ ((rb & 7) << 4)));
            }
#pragma unroll
            for (int i = 0; i < MI; ++i)
#pragma unroll
                for (int j = 0; j < NJ; ++j)
                    acc[i][j] = __builtin_amdgcn_mfma_f32_16x16x32_bf16(
                        a[i], b[j], acc[i][j], 0, 0, 0);
        }
        __syncthreads();
        cur ^= 1;
    }

    if (POOL) {
        float* red = (float*)Asl;
        red[tid] = 0.f;
        __syncthreads();
#pragma unroll
        for (int j = 0; j < NJ; ++j) {
            const int c = wn * (BN / 2) + j * 16 + (lane & 15);
            const float bi = BIAS ? bias[col0 + c] : 0.f;
            float s = 0.f;
#pragma unroll
            for (int i = 0; i < MI; ++i) {
                f32x4 v = acc[i][j];
#pragma unroll
                for (int r2 = 0; r2 < 4; ++r2) {
                    float val = v[r2] * alpha + bi;
                    if (RELU) val = fmaxf(val, 0.f);
                    s += val;
                }
            }
            atomicAdd(&red[wm * BN + c], s);
        }
        __syncthreads();
        float* C = (float*)Cout + bz * cBatch;
        const int pm = tid >> 7, c = tid & 127;
        C[(size_t)(row0 / 64 + pm) * ldc + col0 + c] = red[pm * BN + c];
    } else if (TRANSV && col0 >= 1024) {
        unsigned short* tr = Asl;   // 64x64 ushort (dead LDS)
#pragma unroll
        for (int i = 0; i < MI; ++i) {
            const int rr = wm * (BM / 2) + i * 16 + (lane >> 4) * 4;
#pragma unroll
            for (int j = 0; j < NJ; ++j) {
                const int c = wn * (BN / 2) + j * 16 + (lane & 15);
                const float bi = BIAS ? bias[col0 + c] : 0.f;
                f32x4 v = acc[i][j];
#pragma unroll
                for (int r2 = 0; r2 < 4; ++r2)
                    tr[(rr + r2) * BN + c] = f2bf(v[r2] * alpha + bi);
            }
        }
        __syncthreads();
        const int c  = tid >> 2;
        const int r4 = (tid & 3) * 16;
        ushort4 o[4];
#pragma unroll
        for (int e = 0; e < 16; ++e)
            ((unsigned short*)o)[e] = tr[(r4 + e) * BN + c];
        unsigned short* dst = vTout + (size_t)(col0 - 1024 + c) * 1024 + row0 + r4;
        *(ushort4*)(dst + 0)  = o[0];
        *(ushort4*)(dst + 4)  = o[1];
        *(ushort4*)(dst + 8)  = o[2];
        *(ushort4*)(dst + 12) = o[3];
    } else if (OUTF32) {
        float* Cf = (float*)Cout + bz * cBatch;
#pragma unroll
        for (int i = 0; i < MI; ++i) {
            const int rg = row0 + wm * (BM / 2) + i * 16 + (lane >> 4) * 4;
#pragma unroll
            for (int j = 0; j < NJ; ++j) {
                const int c = col0 + wn * (BN / 2) + j * 16 + (lane & 15);
                const float bi = BIAS ? bias[c] : 0.f;
                f32x4 v = acc[i][j];
#pragma unroll
                for (int r2 = 0; r2 < 4; ++r2) {
                    float val = v[r2] * alpha + bi;
                    if (RELU) val = fmaxf(val, 0.f);
                    if (RESID) val += resid[(size_t)(rg + r2) * ldr + c];
                    Cf[(size_t)(rg + r2) * ldc + c] = val;
                    if (BOTH) vTout[(size_t)(rg + r2) * ldc + c] = f2bf(val);
                }
            }
        }
    } else {
        // bf16 output: LDS-bounce -> 16B/lane coalesced stores (r15).
        // 64-row chunks; 64*BN ushorts fit in Asl (8 KB..16 KB).
        unsigned short* Cu = (unsigned short*)Cout + bz * cBatch;
        unsigned short* bounce = Asl;
        constexpr int NCH = BM / 64;
#pragma unroll
        for (int ch = 0; ch < NCH; ++ch) {
            if (NCH == 1 || wm == ch) {
#pragma unroll
                for (int i = 0; i < MI; ++i) {
                    const int lr0 = (NCH == 1 ? wm * (BM / 2) : 0) + i * 16 + (lane >> 4) * 4;
#pragma unroll
                    for (int j = 0; j < NJ; ++j) {
                        const int c = wn * (BN / 2) + j * 16 + (lane & 15);
                        const float bi = BIAS ? bias[col0 + c] : 0.f;
                        f32x4 v = acc[i][j];
#pragma unroll
                        for (int r2 = 0; r2 < 4; ++r2) {
                            float val = v[r2] * alpha + bi;
                            if (RELU) val = fmaxf(val, 0.f);
                            bounce[(lr0 + r2) * BN + c] = f2bf(val);
                        }
                    }
                }
            }
            __syncthreads();
#pragma unroll
            for (int e = 0; e < BN / 32; ++e) {
                const int idx = e * 2048 + tid * 8;      // 2048 elems per pass
                const int row = idx / BN, col = idx % BN;
                uint4 v = *(uint4*)&bounce[row * BN + col];
                *(uint4*)(Cu + (size_t)(row0 + ch * 64 + row) * ldc + col0 + col) = v;
            }
            if (ch + 1 < NCH) __syncthreads();
        }
    }
}

// ---------------------------------------------------------------------------
// Flash attention KV-split (r14): grid (16, NH, 2); block z handles K/V tiles
// [z*8, z*8+8), writes raw partial O (f32) + per-(z,h,row) m,l. Double-
// buffered K/V (r13).
// ---------------------------------------------------------------------------
__global__ __launch_bounds__(256) void flash_attn(
    const unsigned short* __restrict__ qkv,   // [1024][1536] (q|k|v)
    const unsigned short* __restrict__ vT,    // [512][1024]
    float* __restrict__ Of,                   // [2][1024][512]
    float* __restrict__ mlb)                  // [2][NH][1024][2]
{
    __shared__ unsigned short Qs[64 * 64];
    __shared__ unsigned short Ks[2][64 * 64];
    __shared__ unsigned short Vs[2][64 * 64];
    __shared__ unsigned short Ps[64 * 64];

    const int tid = threadIdx.x, wave = tid >> 6, lane = tid & 63;
    const int q0 = blockIdx.x * 64;
    const int h  = blockIdx.y;
    const int z  = blockIdx.z;
    const int kt0 = z * 8;

    stage_tile<2>(qkv + (size_t)q0 * 1536 + h * 64, 1536, Qs, wave, lane);
    stage_tile<2>(qkv + 512 + (size_t)(kt0 * 64) * 1536 + h * 64, 1536, Ks[0], wave, lane);
    stage_tile<2>(vT + (size_t)(h * 64) * 1024 + kt0 * 64, 1024, Vs[0], wave, lane);
    __syncthreads();

    f32x4 Oacc[4];
#pragma unroll
    for (int j = 0; j < 4; ++j) Oacc[j] = (f32x4){0.f, 0.f, 0.f, 0.f};
    float mrow[4] = {-1e30f, -1e30f, -1e30f, -1e30f};
    float lrow[4] = {0.f, 0.f, 0.f, 0.f};

    for (int kt = 0; kt < 8; ++kt) {
        if (kt < 7) {
            stage_tile<2>(qkv + 512 + (size_t)((kt0 + kt + 1) * 64) * 1536 + h * 64, 1536,
                          Ks[(kt + 1) & 1], wave, lane);
            stage_tile<2>(vT + (size_t)(h * 64) * 1024 + (kt0 + kt + 1) * 64, 1024,
                          Vs[(kt + 1) & 1], wave, lane);
        }
        const unsigned short* Kc = Ks[kt & 1];
        const unsigned short* Vc = Vs[kt & 1];

        f32x4 s[4];
#pragma unroll
        for (int j = 0; j < 4; ++j) s[j] = (f32x4){0.f, 0.f, 0.f, 0.f};
#pragma unroll
        for (int ks = 0; ks < 2; ++ks) {
            const int kbase = ks * 64 + (lane >> 4) * 16;
            const int ra = wave * 16 + (lane & 15);
            short8 aq = *(const short8*)((const char*)Qs + ra * 128 + (kbase ^ ((ra & 7) << 4)));
#pragma unroll
            for (int j = 0; j < 4; ++j) {
                const int rb = j * 16 + (lane & 15);
                short8 bk8 = *(const short8*)((const char*)Kc + rb * 128 + (kbase ^ ((rb & 7) << 4)));
                s[j] = __builtin_amdgcn_mfma_f32_16x16x32_bf16(aq, bk8, s[j], 0, 0, 0);
            }
        }

        float f[4];
#pragma unroll
        for (int r = 0; r < 4; ++r) {
            float mx = -1e30f;
#pragma unroll
            for (int j = 0; j < 4; ++j) { s[j][r] *= 0.125f; mx = fmaxf(mx, s[j][r]); }
#pragma unroll
            for (int o = 1; o < 16; o <<= 1) mx = fmaxf(mx, __shfl_xor(mx, o));
            const float mn = fmaxf(mrow[r], mx);
            f[r] = expf(mrow[r] - mn);
            mrow[r] = mn;
            float sm = 0.f;
#pragma unroll
            for (int j = 0; j < 4; ++j) { s[j][r] = expf(s[j][r] - mn); sm += s[j][r]; }
#pragma unroll
            for (int o = 1; o < 16; o <<= 1) sm += __shfl_xor(sm, o);
            lrow[r] = lrow[r] * f[r] + sm;
        }
#pragma unroll
        for (int j = 0; j < 4; ++j)
#pragma unroll
            for (int r = 0; r < 4; ++r) Oacc[j][r] *= f[r];

        // P (C-layout) -> LDS (swizzled); wave-local stripe, no barrier needed
#pragma unroll
        for (int j = 0; j < 4; ++j) {
            const int col = (lane & 15) + j * 16;
#pragma unroll
            for (int r = 0; r < 4; ++r) {
                const int row = wave * 16 + (lane >> 4) * 4 + r;
                *(unsigned short*)((char*)Ps + row * 128 + ((col * 2) ^ ((row & 7) << 4))) =
                    f2bf(s[j][r]);
            }
        }

#pragma unroll
        for (int ks = 0; ks < 2; ++ks) {
            const int kbase = ks * 64 + (lane >> 4) * 16;
            const int ra = wave * 16 + (lane & 15);
            short8 ap = *(const short8*)((const char*)Ps + ra * 128 + (kbase ^ ((ra & 7) << 4)));
#pragma unroll
            for (int j = 0; j < 4; ++j) {
                const int rb = j * 16 + (lane & 15);
                short8 bv8 = *(const short8*)((const char*)Vc + rb * 128 + (kbase ^ ((rb & 7) << 4)));
                Oacc[j] = __builtin_amdgcn_mfma_f32_16x16x32_bf16(ap, bv8, Oacc[j], 0, 0, 0);
            }
        }
        __syncthreads();
    }

    float* Oz = Of + (size_t)z * 524288;
#pragma unroll
    for (int j = 0; j < 4; ++j) {
        const int c = h * 64 + j * 16 + (lane & 15);
#pragma unroll
        for (int r = 0; r < 4; ++r) {
            const int row = q0 + wave * 16 + (lane >> 4) * 4 + r;
            Oz[(size_t)row * D_ + c] = Oacc[j][r];
        }
    }
    if ((lane & 15) == 0) {
#pragma unroll
        for (int r = 0; r < 4; ++r) {
            const int row = q0 + wave * 16 + (lane >> 4) * 4 + r;
            float* dst = mlb + (((size_t)z * NH + h) * 1024 + row) * 2;
            dst[0] = mrow[r];
            dst[1] = lrow[r];
        }
    }
}

// ---------------------------------------------------------------------------
// Merge the two KV-split partials (per head-row m,l).
// ---------------------------------------------------------------------------
__global__ __launch_bounds__(256) void flash_merge(
    const float* __restrict__ Of, const float* __restrict__ mlb,
    unsigned short* __restrict__ O)
{
    const int tid = threadIdx.x;
    const int row = blockIdx.x * 4 + (tid >> 6);
    const int lane = tid & 63;
    const int d0 = lane * 8;
    const int h = d0 >> 6;
    const float* ml0 = mlb + (((size_t)0 * NH + h) * 1024 + row) * 2;
    const float* ml1 = mlb + (((size_t)1 * NH + h) * 1024 + row) * 2;
    const float m0 = ml0[0], l0 = ml0[1], m1 = ml1[0], l1 = ml1[1];
    const float m = fmaxf(m0, m1);
    const float a0 = expf(m0 - m), a1 = expf(m1 - m);
    const float inv = 1.0f / (a0 * l0 + a1 * l1);
    const float* p0 = Of + (size_t)row * D_ + d0;
    const float* p1 = Of + 524288 + (size_t)row * D_ + d0;
    float4 x0 = *(const float4*)p0, x1 = *(const float4*)(p0 + 4);
    float4 y0 = *(const float4*)p1, y1 = *(const float4*)(p1 + 4);
    ushort4 o0, o1;
    o0.x = f2bf((a0 * x0.x + a1 * y0.x) * inv);
    o0.y = f2bf((a0 * x0.y + a1 * y0.y) * inv);
    o0.z = f2bf((a0 * x0.z + a1 * y0.z) * inv);
    o0.w = f2bf((a0 * x0.w + a1 * y0.w) * inv);
    o1.x = f2bf((a0 * x1.x + a1 * y1.x) * inv);
    o1.y = f2bf((a0 * x1.y + a1 * y1.y) * inv);
    o1.z = f2bf((a0 * x1.z + a1 * y1.z) * inv);
    o1.w = f2bf((a0 * x1.w + a1 * y1.w) * inv);
    *(ushort4*)(O + (size_t)row * D_ + d0) = o0;
    *(ushort4*)(O + (size_t)row * D_ + d0 + 4) = o1;
}

// ---------------------------------------------------------------------------
// LN over y = x(resid) + bias + sum of NZ split-K partials. One wave per row.
// ---------------------------------------------------------------------------
template<int NZ>
__global__ __launch_bounds__(64) void ln_sum_kernel(
    const float* __restrict__ y4,     // [NZ][1024][512]
    const float* __restrict__ bias,   // [512]
    const float* __restrict__ w, const float* __restrict__ b,
    float* __restrict__ x, unsigned short* __restrict__ xb)
{
    const int row = blockIdx.x;
    const int lane = threadIdx.x;
    const size_t off = (size_t)row * 512 + lane * 8;
    float vals[8];
#pragma unroll
    for (int j = 0; j < 8; ++j) vals[j] = x[off + j] + bias[lane * 8 + j];
#pragma unroll
    for (int z = 0; z < NZ; ++z) {
        float4 p0 = *(const float4*)(y4 + (size_t)z * 524288 + off);
        float4 p1 = *(const float4*)(y4 + (size_t)z * 524288 + off + 4);
        vals[0] += p0.x; vals[1] += p0.y; vals[2] += p0.z; vals[3] += p0.w;
        vals[4] += p1.x; vals[5] += p1.y; vals[6] += p1.z; vals[7] += p1.w;
    }
    float s = 0.f;
#pragma unroll
    for (int j = 0; j < 8; ++j) s += vals[j];
#pragma unroll
    for (int o = 32; o >= 1; o >>= 1) s += __shfl_xor(s, o);
    const float mu = s * (1.f / 512.f);
    float q = 0.f;
#pragma unroll
    for (int j = 0; j < 8; ++j) { float d = vals[j] - mu; q += d * d; }
#pragma unroll
    for (int o = 32; o >= 1; o >>= 1) q += __shfl_xor(q, o);
    const float inv = 1.0f / sqrtf(q * (1.f / 512.f) + EPS_);
    float ov[8];
#pragma unroll
    for (int j = 0; j < 8; ++j)
        ov[j] = (vals[j] - mu) * inv * w[lane * 8 + j] + b[lane * 8 + j];
    float4 o0 = {ov[0], ov[1], ov[2], ov[3]};
    float4 o1 = {ov[4], ov[5], ov[6], ov[7]};
    *(float4*)(x + off) = o0;
    *(float4*)(x + off + 4) = o1;
    ushort4 u0, u1;
    u0.x = f2bf(ov[0]); u0.y = f2bf(ov[1]); u0.z = f2bf(ov[2]); u0.w = f2bf(ov[3]);
    u1.x = f2bf(ov[4]); u1.y = f2bf(ov[5]); u1.z = f2bf(ov[6]); u1.w = f2bf(ov[7]);
    *(ushort4*)(xb + off) = u0;
    *(ushort4*)(xb + off + 4) = u1;
}

// ---------------------------------------------------------------------------
// Fused values+scatter: compute only the 2048 selected (r,c) dot products.
// ---------------------------------------------------------------------------
__global__ __launch_bounds__(256) void scatter_dot(
    const int* __restrict__ rows, const int* __restrict__ cols,
    const unsigned short* __restrict__ xb, __hip_bfloat16* __restrict__ out)
{
    const int k = blockIdx.x * 4 + (threadIdx.x >> 6);
    const int lane = threadIdx.x & 63;
    const int r = rows[k], c = cols[k];
    const unsigned short* xr = xb + (size_t)r * 512 + lane * 8;
    const unsigned short* xc = xb + (size_t)c * 512 + lane * 8;
    ushort4 a0 = *(const ushort4*)xr, a1 = *(const ushort4*)(xr + 4);
    ushort4 b0 = *(const ushort4*)xc, b1 = *(const ushort4*)(xc + 4);
    float s = bf2f(a0.x) * bf2f(b0.x) + bf2f(a0.y) * bf2f(b0.y) +
              bf2f(a0.z) * bf2f(b0.z) + bf2f(a0.w) * bf2f(b0.w) +
              bf2f(a1.x) * bf2f(b1.x) + bf2f(a1.y) * bf2f(b1.y) +
              bf2f(a1.z) * bf2f(b1.z) + bf2f(a1.w) * bf2f(b1.w);
#pragma unroll
    for (int o = 32; o >= 1; o >>= 1) s += __shfl_xor(s, o);
    if (lane == 0) {
        if (!(fabsf(s) < 1e30f)) s = 0.f;
        out[(size_t)r * 1024 + c] = __float2bfloat16(s);
    }
}

// ---------------------------------------------------------------------------
extern "C" void kernel_launch(void* const* d_in, const int* in_sizes, int n_in,
                              void* d_out, int out_size, void* d_ws, size_t ws_size,
                              hipStream_t stream)
{
    const float* ideal  = (const float*)d_in[0];
    const int*   rows   = (const int*)d_in[1];
    const int*   cols   = (const int*)d_in[2];
    const float* Wm     = (const float*)d_in[3];
    const float* bm     = (const float*)d_in[4];
    const float* Wphi1  = (const float*)d_in[5];
    const float* bphi1  = (const float*)d_in[6];
    const float* Wphi2  = (const float*)d_in[7];
    const float* bphi2  = (const float*)d_in[8];
    const float* Wrho1  = (const float*)d_in[9];
    const float* brho1  = (const float*)d_in[10];
    const float* Wrho2  = (const float*)d_in[11];
    const float* brho2  = (const float*)d_in[12];
    const float* Wq     = (const float*)d_in[13];
    const float* bq     = (const float*)d_in[14];
    const float* Wk     = (const float*)d_in[15];
    const float* bk     = (const float*)d_in[16];
    const float* Wv     = (const float*)d_in[17];
    const float* bv     = (const float*)d_in[18];
    const float* Wo     = (const float*)d_in[19];
    const float* bo     = (const float*)d_in[20];
    const float* ln1w   = (const float*)d_in[21];
    const float* ln1b   = (const float*)d_in[22];
    const float* W1     = (const float*)d_in[23];
    const float* b1     = (const float*)d_in[24];
    const float* W2     = (const float*)d_in[25];
    const float* b2     = (const float*)d_in[26];
    const float* ln2w   = (const float*)d_in[27];
    const float* ln2b   = (const float*)d_in[28];
    __hip_bfloat16* out = (__hip_bfloat16*)d_out;

    // ---- Workspace (MB offsets; ws_size = 256 MiB, round-6 evidence) ----
    char* base = (char*)d_ws;
    unsigned short* w_phi1 = (unsigned short*)(base + (0ll  << 20));
    unsigned short* w_phi2 = (unsigned short*)(base + (1ll  << 20));
    unsigned short* w_rho1 = (unsigned short*)(base + (3ll  << 20));
    unsigned short* w_rho2 = (unsigned short*)(base + (5ll  << 20));
    unsigned short* w_qkv  = (unsigned short*)(base + (6ll  << 20));
    unsigned short* w_o    = (unsigned short*)(base + (12ll << 20));
    unsigned short* w_1    = (unsigned short*)(base + (14ll << 20));
    unsigned short* w_2    = (unsigned short*)(base + (22ll << 20));
    float*          b_qkvc = (float*)         (base + (30ll << 20));
    unsigned short* h0b    = (unsigned short*)(base + (31ll << 20));  // 64MB
    unsigned short* h1b    = (unsigned short*)(base + (95ll << 20));  // 128MB
    float*          sbuf   = (float*)         (base + (223ll << 20)); // 4MB
    unsigned short* id_pad = (unsigned short*)(base + (227ll << 20)); // 8MB
    unsigned short* wm_pad = (unsigned short*)(base + (236ll << 20)); // 64KB
    unsigned short* sb_b   = (unsigned short*)(base + (31ll << 20));
    unsigned short* tb_b   = (unsigned short*)(base + (33ll << 20));
    float*          xbuf   = (float*)         (base + (35ll << 20));
    unsigned short* xb     = (unsigned short*)(base + (37ll << 20));
    unsigned short* qkvb   = (unsigned short*)(base + (40ll << 20));
    unsigned short* vT     = (unsigned short*)(base + (43ll << 20));
    unsigned short* ob     = (unsigned short*)(base + (44ll << 20));
    unsigned short* ffnt   = (unsigned short*)(base + (45ll << 20));  // 4MB
    float*          ysplit = (float*)         (base + (49ll << 20));  // 8MB
    float*          Of     = (float*)         (base + (57ll << 20));  // 4MB
    float*          mlb    = (float*)         (base + (61ll << 20));  // 128KB

    // ---------------- One mega conversion launch ----------------
    mega_cvt<<<17936, 256, 0, stream>>>(
        Wphi1, Wphi2, Wrho1, Wrho2, Wo, W1, W2,
        w_phi1, w_phi2, w_rho1, w_rho2, w_o, w_1, w_2,
        Wq, Wk, Wv, bq, bk, bv, w_qkv, b_qkvc,
        ideal, id_pad, Wm, wm_pad, (unsigned short*)out);

    // ---------------- DeepSets ----------------
    // embed as K=64 MFMA GEMM (bf16 out -> new coalesced epilogue)
    mfma_nt<128, 128, 0, false, true, true, false, false, false, false, false>
        <<<dim3(4, 512), 256, 0, stream>>>(
        id_pad, 0, 64, wm_pad, 0, 64, bm, nullptr, 0, h0b, 0, D_, 64, 1.0f, nullptr);
    // phi1 (MODE 2; bf16 out -> coalesced epilogue fixes the r14 write-bound)
    mfma_nt<128, 128, 2, false, true, true, false, false, false, false, false>
        <<<4096, 256, 0, stream>>>(
        h0b, 0, D_, w_phi1, 0, D_, bphi1, nullptr, 0, h1b, 0, HID_, D_, 1.0f, nullptr);
    // phi2+pool (MODE 2)
    mfma_nt<128, 128, 2, true, true, true, true, false, false, false, false>
        <<<4096, 256, 0, stream>>>(
        h1b, 0, HID_, w_phi2, 0, HID_, bphi2, nullptr, 0, sbuf, 0, HID_, HID_, 1.0f, nullptr);

    // rho (64^2 tiles, DBUF); rho2 writes BOTH xbuf f32 + xb bf16
    cvt_bf16_kernel<<<1024, 256, 0, stream>>>(sbuf, sb_b, 262144);
    mfma_nt<64, 64, 0, false, true, true, false, false, false, true, false>
        <<<dim3(16, 16), 256, 0, stream>>>(
        sb_b, 0, HID_, w_rho1, 0, HID_, brho1, nullptr, 0, tb_b, 0, HID_, HID_, 1.0f, nullptr);
    mfma_nt<64, 64, 0, true, true, true, false, false, false, true, true>
        <<<dim3(8, 16), 256, 0, stream>>>(
        tb_b, 0, HID_, w_rho2, 0, HID_, brho2, nullptr, 0, xbuf, 0, D_, HID_, 1.0f, xb);

    // ---------------- Transformer ----------------
    for (int l = 0; l < NL; ++l) {
        // QKV fused (TRANSV writes vT for V-region blocks)
        mfma_nt<64, 64, 0, false, true, false, false, false, true, true, false>
            <<<dim3(24, 16), 256, 0, stream>>>(
            xb, 0, D_, w_qkv + (long long)l * 1536 * D_, 0, D_, b_qkvc + l * 1536,
            nullptr, 0, qkvb, 0, 1536, D_, 1.0f, vT);
        // flash attention KV-split-2 + merge
        flash_attn<<<dim3(16, NH, 2), 256, 0, stream>>>(qkvb, vT, Of, mlb);
        flash_merge<<<256, 256, 0, stream>>>(Of, mlb, ob);
        // Wo split-K=2 -> partials; ln_sum<2> folds bias+resid+LN1
        mfma_nt<64, 64, 0, true, false, false, false, false, false, true, false>
            <<<dim3(8, 16, 2), 256, 0, stream>>>(
            ob, 256, D_, w_o + (long long)l * D_ * D_, 256, D_, nullptr,
            nullptr, 0, ysplit, 524288, D_, 256, 1.0f, nullptr);
        ln_sum_kernel<2><<<NP, 64, 0, stream>>>(ysplit, bo + l * D_,
                                                ln1w + l * D_, ln1b + l * D_, xbuf, xb);
        // ffn1: xb @ W1^T + b1, relu -> bf16
        mfma_nt<64, 64, 0, false, true, true, false, false, false, true, false>
            <<<dim3(32, 16), 256, 0, stream>>>(
            xb, 0, D_, w_1 + (long long)l * FF_ * D_, 0, D_, b1 + l * FF_,
            nullptr, 0, ffnt, 0, FF_, D_, 1.0f, nullptr);
        // ffn2 split-K=4 -> partials; ln_sum<4> folds bias+resid+LN2
        mfma_nt<64, 64, 0, true, false, false, false, false, false, true, false>
            <<<dim3(8, 16, 4), 256, 0, stream>>>(
            ffnt, 512, FF_, w_2 + (long long)l * D_ * FF_, 512, FF_, nullptr,
            nullptr, 0, ysplit, 524288, D_, 512, 1.0f, nullptr);
        ln_sum_kernel<4><<<NP, 64, 0, stream>>>(ysplit, b2 + l * D_,
                                                ln2w + l * D_, ln2b + l * D_, xbuf, xb);
    }

    // scatter: out[r,c] = dot(x[r], x[c]) for the 2048 selected pairs only
    scatter_dot<<<NK / 4, 256, 0, stream>>>(rows, cols, xb, out);
}

// Round 16
// 577.786 us; speedup vs baseline: 1.0311x; 1.0311x over previous
//
#include <hip/hip_runtime.h>
#include <hip/hip_bf16.h>

// Problem constants
#define NP    1024   // polynomials
#define NM    64     // monomials per poly
#define MD_   16
#define D_    512
#define NH    8
#define DH_   64
#define NL    4
#define FF_   2048
#define HID_  1024
#define NK    2048
#define EPS_  1e-5f

typedef __attribute__((ext_vector_type(8))) short short8;
typedef __attribute__((ext_vector_type(4))) float f32x4;

static __device__ __forceinline__ unsigned short f2bf(float f) {
    __hip_bfloat16 h = __float2bfloat16(f);
    return *reinterpret_cast<unsigned short*>(&h);
}
static __device__ __forceinline__ float bf2f(unsigned short u) {
    unsigned int x = ((unsigned int)u) << 16;
    return __uint_as_float(x);
}

// ---------------------------------------------------------------------------
// MEGA conversion kernel (r14): output sentinel fill + all weight converts +
// QKV pack + bias gather + K=64 pads in ONE launch. 17936 blocks.
// ---------------------------------------------------------------------------
__global__ __launch_bounds__(256) void mega_cvt(
    const float* __restrict__ Wphi1, const float* __restrict__ Wphi2,
    const float* __restrict__ Wrho1, const float* __restrict__ Wrho2,
    const float* __restrict__ Wo,    const float* __restrict__ W1,
    const float* __restrict__ W2,
    unsigned short* __restrict__ w_phi1, unsigned short* __restrict__ w_phi2,
    unsigned short* __restrict__ w_rho1, unsigned short* __restrict__ w_rho2,
    unsigned short* __restrict__ w_o,    unsigned short* __restrict__ w_1,
    unsigned short* __restrict__ w_2,
    const float* __restrict__ Wq, const float* __restrict__ Wk,
    const float* __restrict__ Wv, const float* __restrict__ bq,
    const float* __restrict__ bk, const float* __restrict__ bv,
    unsigned short* __restrict__ w_qkv, float* __restrict__ b_qkvc,
    const float* __restrict__ ideal, unsigned short* __restrict__ id_pad,
    const float* __restrict__ Wm,    unsigned short* __restrict__ wm_pad,
    unsigned short* __restrict__ out)
{
    const int b = blockIdx.x, t = threadIdx.x;
    if (b < 512) {
        // output sentinel: 0xFBFF finite under bf16/fp16/fp32 views (r0-3 lesson)
        const long long i = (long long)b * 256 + t;
        const unsigned int pat = 0xFBFFFBFFu;
        uint4 v = {pat, pat, pat, pat};
        *(uint4*)(out + i * 8) = v;
    } else if (b < 12800) {
        const int i = (b - 512) * 256 + t;   // f4 index < 3145728
        const float* src; unsigned short* dst; int l;
        if      (i <  131072) { src = Wphi1; dst = w_phi1; l = i; }
        else if (i <  393216) { src = Wphi2; dst = w_phi2; l = i -  131072; }
        else if (i <  655360) { src = Wrho1; dst = w_rho1; l = i -  393216; }
        else if (i <  786432) { src = Wrho2; dst = w_rho2; l = i -  655360; }
        else if (i < 1048576) { src = Wo;    dst = w_o;    l = i -  786432; }
        else if (i < 2097152) { src = W1;    dst = w_1;    l = i - 1048576; }
        else                  { src = W2;    dst = w_2;    l = i - 2097152; }
        float4 v = *(const float4*)(src + (size_t)l * 4);
        ushort4 o;
        o.x = f2bf(v.x); o.y = f2bf(v.y); o.z = f2bf(v.z); o.w = f2bf(v.w);
        *(ushort4*)(dst + (size_t)l * 4) = o;
    } else if (b < 15872) {
        const int g = (b - 12800) >> 8;      // 0..11
        const int inner = (b - 12800) & 255;
        const int part = g % 3, l = g / 3;
        const float* src  = (part == 0 ? Wq : part == 1 ? Wk : Wv) + (size_t)l * D_ * D_;
        const float* bsrc = (part == 0 ? bq : part == 1 ? bk : bv) + l * D_;
        unsigned short* dst = w_qkv + (size_t)l * 1536 * D_ + (size_t)part * 512 * D_;
        const int i = inner * 256 + t;       // f4 index < 65536
        float4 v = *(const float4*)(src + (size_t)i * 4);
        ushort4 o;
        o.x = f2bf(v.x); o.y = f2bf(v.y); o.z = f2bf(v.z); o.w = f2bf(v.w);
        *(ushort4*)(dst + (size_t)i * 4) = o;
        if (inner == 0) {
            b_qkvc[l * 1536 + part * 512 + t * 2]     = bsrc[t * 2];
            b_qkvc[l * 1536 + part * 512 + t * 2 + 1] = bsrc[t * 2 + 1];
        }
    } else {
        // pad-convert [nrows][16] f32 -> [nrows][64] bf16 (cols 16..63 = 0)
        const float* src; unsigned short* dst; int row;
        if (b < 17920) { src = ideal; dst = id_pad; row = (b - 15872) * 32 + (t >> 3); }
        else           { src = Wm;    dst = wm_pad; row = (b - 17920) * 32 + (t >> 3); }
        const int c8 = (t & 7) * 8;
        ushort4 o0 = {0, 0, 0, 0}, o1 = {0, 0, 0, 0};
        if (c8 < 16) {
            float4 a = *(const float4*)(src + (size_t)row * 16 + c8);
            float4 bb = *(const float4*)(src + (size_t)row * 16 + c8 + 4);
            o0.x = f2bf(a.x);  o0.y = f2bf(a.y);  o0.z = f2bf(a.z);  o0.w = f2bf(a.w);
            o1.x = f2bf(bb.x); o1.y = f2bf(bb.y); o1.z = f2bf(bb.z); o1.w = f2bf(bb.w);
        }
        *(ushort4*)(dst + (size_t)row * 64 + c8) = o0;
        *(ushort4*)(dst + (size_t)row * 64 + c8 + 4) = o1;
    }
}

__global__ __launch_bounds__(256) void cvt_bf16_kernel(
    const float* __restrict__ in, unsigned short* __restrict__ out, int n4)
{
    const int i = blockIdx.x * 256 + threadIdx.x;
    if (i < n4) {
        float4 v = *(const float4*)(in + (size_t)i * 4);
        ushort4 o;
        o.x = f2bf(v.x); o.y = f2bf(v.y); o.z = f2bf(v.z); o.w = f2bf(v.w);
        *(ushort4*)(out + (size_t)i * 4) = o;
    }
}

// ---------------------------------------------------------------------------
// Staging via global_load_lds, pre-swizzled source (G21). Validated round 8.
// ---------------------------------------------------------------------------
template<int ISSUES>
static __device__ __forceinline__ void stage_tile(
    const unsigned short* __restrict__ src, int ld,
    unsigned short* lds, int wave, int lane)
{
    const int rl  = lane >> 3;
    const int sw8 = (((lane & 7) ^ rl) << 3);
#pragma unroll
    for (int i = 0; i < ISSUES; ++i) {
        const int rbase = i * 32 + wave * 8;
        const unsigned short* g = src + (size_t)(rbase + rl) * ld + sw8;
        unsigned short* l = lds + rbase * 64;
        __builtin_amdgcn_global_load_lds(
            (const __attribute__((address_space(1))) void*)g,
            (__attribute__((address_space(3))) void*)l, 16, 0, 0);
    }
}

// ---------------------------------------------------------------------------
// Unified MFMA bf16 NT GEMM (r14 configuration — r15's LDS-bounce bf16
// epilogue REVERTED: phi WRITE_SIZE was only 4 MB (L3 absorbs the bf16 C
// writes), so scalar stores were never the bottleneck and the bounce's extra
// barriers cost +22 us). MODE 2: XCD-aligned 1-D decode (r10). TRANSV: QKV
// V-region writes transposed vT. DBUF (r13): double-buffered K-loop.
// BOTH (r14): f32 + bf16 mirror outputs.
// ---------------------------------------------------------------------------
template<int BM, int BN, int MODE, bool OUTF32, bool BIAS, bool RELU, bool POOL,
         bool RESID, bool TRANSV, bool DBUF, bool BOTH>
__global__ __launch_bounds__(256) void mfma_nt(
    const unsigned short* __restrict__ A, long long aBatch, int lda,
    const unsigned short* __restrict__ W, long long bBatch, int ldb,
    const float* __restrict__ bias,
    const float* __restrict__ resid, int ldr,
    void* __restrict__ Cout, long long cBatch, int ldc,
    int K, float alpha, unsigned short* __restrict__ vTout)
{
    constexpr int BK = 64;
    constexpr int MI = BM / 32, NJ = BN / 32;
    __shared__ unsigned short Asl[(DBUF ? 2 : 1) * BM * BK];
    __shared__ unsigned short Bsl[(DBUF ? 2 : 1) * BN * BK];

    const int tid  = threadIdx.x;
    const int wave = tid >> 6, lane = tid & 63;
    const int wm = wave >> 1, wn = wave & 1;
    int row0, col0;
    if (MODE == 2) {
        const int f = blockIdx.x;
        const int lo = f & 7, mid = (f >> 3) & 7, hi = f >> 6;
        row0 = (hi * 8 + lo) * BM;
        col0 = mid * BN;
    } else {
        row0 = blockIdx.y * BM;
        col0 = blockIdx.x * BN;
    }
    const long long bz = blockIdx.z;
    A += bz * aBatch + (size_t)row0 * lda;
    W += bz * bBatch + (size_t)col0 * ldb;

    f32x4 acc[MI][NJ];
#pragma unroll
    for (int i = 0; i < MI; ++i)
#pragma unroll
        for (int j = 0; j < NJ; ++j) acc[i][j] = (f32x4){0.f, 0.f, 0.f, 0.f};

    if (DBUF) {
        stage_tile<MI>(A, lda, Asl, wave, lane);
        stage_tile<NJ>(W, ldb, Bsl, wave, lane);
        __syncthreads();
    }
    int cur = 0;
    for (int k0 = 0; k0 < K; k0 += BK) {
        const unsigned short *Ac, *Bc;
        if (DBUF) {
            if (k0 + BK < K) {
                stage_tile<MI>(A + k0 + BK, lda, Asl + (cur ^ 1) * BM * BK, wave, lane);
                stage_tile<NJ>(W + k0 + BK, ldb, Bsl + (cur ^ 1) * BN * BK, wave, lane);
            }
            Ac = Asl + cur * BM * BK;
            Bc = Bsl + cur * BN * BK;
        } else {
            stage_tile<MI>(A + k0, lda, Asl, wave, lane);
            stage_tile<NJ>(W + k0, ldb, Bsl, wave, lane);
            __syncthreads();
            Ac = Asl; Bc = Bsl;
        }
#pragma unroll
        for (int ks = 0; ks < 2; ++ks) {
            short8 a[MI], b[NJ];
            const int kbase = ks * 64 + (lane >> 4) * 16;
#pragma unroll
            for (int i = 0; i < MI; ++i) {
                const int ra = wm * (BM / 2) + i * 16 + (lane & 15);
                a[i] = *(const short8*)((const char*)Ac + ra * 128 + (kbase ^ ((ra & 7) << 4)));
            }
#pragma unroll
            for (int j = 0; j < NJ; ++j) {
                const int rb = wn * (BN / 2) + j * 16 + (lane & 15);
                b[j] = *(const short8*)((const char*)Bc + rb * 128 + (kbase ^ ((rb & 7) << 4)));
            }
#pragma unroll
            for (int i = 0; i < MI; ++i)
#pragma unroll
                for (int j = 0; j < NJ; ++j)
                    acc[i][j] = __builtin_amdgcn_mfma_f32_16x16x32_bf16(
                        a[i], b[j], acc[i][j], 0, 0, 0);
        }
        __syncthreads();
        cur ^= 1;
    }

    if (POOL) {
        float* red = (float*)Asl;
        red[tid] = 0.f;
        __syncthreads();
#pragma unroll
        for (int j = 0; j < NJ; ++j) {
            const int c = wn * (BN / 2) + j * 16 + (lane & 15);
            const float bi = BIAS ? bias[col0 + c] : 0.f;
            float s = 0.f;
#pragma unroll
            for (int i = 0; i < MI; ++i) {
                f32x4 v = acc[i][j];
#pragma unroll
                for (int r2 = 0; r2 < 4; ++r2) {
                    float val = v[r2] * alpha + bi;
                    if (RELU) val = fmaxf(val, 0.f);
                    s += val;
                }
            }
            atomicAdd(&red[wm * BN + c], s);
        }
        __syncthreads();
        float* C = (float*)Cout + bz * cBatch;
        const int pm = tid >> 7, c = tid & 127;
        C[(size_t)(row0 / 64 + pm) * ldc + col0 + c] = red[pm * BN + c];
    } else if (TRANSV && col0 >= 1024) {
        unsigned short* tr = Asl;   // 64x64 ushort (dead LDS)
#pragma unroll
        for (int i = 0; i < MI; ++i) {
            const int rr = wm * (BM / 2) + i * 16 + (lane >> 4) * 4;
#pragma unroll
            for (int j = 0; j < NJ; ++j) {
                const int c = wn * (BN / 2) + j * 16 + (lane & 15);
                const float bi = BIAS ? bias[col0 + c] : 0.f;
                f32x4 v = acc[i][j];
#pragma unroll
                for (int r2 = 0; r2 < 4; ++r2)
                    tr[(rr + r2) * BN + c] = f2bf(v[r2] * alpha + bi);
            }
        }
        __syncthreads();
        const int c  = tid >> 2;
        const int r4 = (tid & 3) * 16;
        ushort4 o[4];
#pragma unroll
        for (int e = 0; e < 16; ++e)
            ((unsigned short*)o)[e] = tr[(r4 + e) * BN + c];
        unsigned short* dst = vTout + (size_t)(col0 - 1024 + c) * 1024 + row0 + r4;
        *(ushort4*)(dst + 0)  = o[0];
        *(ushort4*)(dst + 4)  = o[1];
        *(ushort4*)(dst + 8)  = o[2];
        *(ushort4*)(dst + 12) = o[3];
    } else {
        float* Cf = (float*)Cout + (OUTF32 ? bz * cBatch : 0);
        unsigned short* Cu = (unsigned short*)Cout + (OUTF32 ? 0 : bz * cBatch);
#pragma unroll
        for (int i = 0; i < MI; ++i) {
            const int rg = row0 + wm * (BM / 2) + i * 16 + (lane >> 4) * 4;
#pragma unroll
            for (int j = 0; j < NJ; ++j) {
                const int c = col0 + wn * (BN / 2) + j * 16 + (lane & 15);
                const float bi = BIAS ? bias[c] : 0.f;
                f32x4 v = acc[i][j];
#pragma unroll
                for (int r2 = 0; r2 < 4; ++r2) {
                    float val = v[r2] * alpha + bi;
                    if (RELU) val = fmaxf(val, 0.f);
                    if (RESID) val += resid[(size_t)(rg + r2) * ldr + c];
                    if (OUTF32) {
                        Cf[(size_t)(rg + r2) * ldc + c] = val;
                        if (BOTH) vTout[(size_t)(rg + r2) * ldc + c] = f2bf(val);
                    } else {
                        Cu[(size_t)(rg + r2) * ldc + c] = f2bf(val);
                    }
                }
            }
        }
    }
}

// ---------------------------------------------------------------------------
// Flash attention KV-split (r14): grid (16, NH, 2); block z handles K/V tiles
// [z*8, z*8+8), writes raw partial O (f32) + per-(z,h,row) m,l. Double-
// buffered K/V (r13).
// ---------------------------------------------------------------------------
__global__ __launch_bounds__(256) void flash_attn(
    const unsigned short* __restrict__ qkv,   // [1024][1536] (q|k|v)
    const unsigned short* __restrict__ vT,    // [512][1024]
    float* __restrict__ Of,                   // [2][1024][512]
    float* __restrict__ mlb)                  // [2][NH][1024][2]
{
    __shared__ unsigned short Qs[64 * 64];
    __shared__ unsigned short Ks[2][64 * 64];
    __shared__ unsigned short Vs[2][64 * 64];
    __shared__ unsigned short Ps[64 * 64];

    const int tid = threadIdx.x, wave = tid >> 6, lane = tid & 63;
    const int q0 = blockIdx.x * 64;
    const int h  = blockIdx.y;
    const int z  = blockIdx.z;
    const int kt0 = z * 8;

    stage_tile<2>(qkv + (size_t)q0 * 1536 + h * 64, 1536, Qs, wave, lane);
    stage_tile<2>(qkv + 512 + (size_t)(kt0 * 64) * 1536 + h * 64, 1536, Ks[0], wave, lane);
    stage_tile<2>(vT + (size_t)(h * 64) * 1024 + kt0 * 64, 1024, Vs[0], wave, lane);
    __syncthreads();

    f32x4 Oacc[4];
#pragma unroll
    for (int j = 0; j < 4; ++j) Oacc[j] = (f32x4){0.f, 0.f, 0.f, 0.f};
    float mrow[4] = {-1e30f, -1e30f, -1e30f, -1e30f};
    float lrow[4] = {0.f, 0.f, 0.f, 0.f};

    for (int kt = 0; kt < 8; ++kt) {
        if (kt < 7) {
            stage_tile<2>(qkv + 512 + (size_t)((kt0 + kt + 1) * 64) * 1536 + h * 64, 1536,
                          Ks[(kt + 1) & 1], wave, lane);
            stage_tile<2>(vT + (size_t)(h * 64) * 1024 + (kt0 + kt + 1) * 64, 1024,
                          Vs[(kt + 1) & 1], wave, lane);
        }
        const unsigned short* Kc = Ks[kt & 1];
        const unsigned short* Vc = Vs[kt & 1];

        f32x4 s[4];
#pragma unroll
        for (int j = 0; j < 4; ++j) s[j] = (f32x4){0.f, 0.f, 0.f, 0.f};
#pragma unroll
        for (int ks = 0; ks < 2; ++ks) {
            const int kbase = ks * 64 + (lane >> 4) * 16;
            const int ra = wave * 16 + (lane & 15);
            short8 aq = *(const short8*)((const char*)Qs + ra * 128 + (kbase ^ ((ra & 7) << 4)));
#pragma unroll
            for (int j = 0; j < 4; ++j) {
                const int rb = j * 16 + (lane & 15);
                short8 bk8 = *(const short8*)((const char*)Kc + rb * 128 + (kbase ^ ((rb & 7) << 4)));
                s[j] = __builtin_amdgcn_mfma_f32_16x16x32_bf16(aq, bk8, s[j], 0, 0, 0);
            }
        }

        float f[4];
#pragma unroll
        for (int r = 0; r < 4; ++r) {
            float mx = -1e30f;
#pragma unroll
            for (int j = 0; j < 4; ++j) { s[j][r] *= 0.125f; mx = fmaxf(mx, s[j][r]); }
#pragma unroll
            for (int o = 1; o < 16; o <<= 1) mx = fmaxf(mx, __shfl_xor(mx, o));
            const float mn = fmaxf(mrow[r], mx);
            f[r] = expf(mrow[r] - mn);
            mrow[r] = mn;
            float sm = 0.f;
#pragma unroll
            for (int j = 0; j < 4; ++j) { s[j][r] = expf(s[j][r] - mn); sm += s[j][r]; }
#pragma unroll
            for (int o = 1; o < 16; o <<= 1) sm += __shfl_xor(sm, o);
            lrow[r] = lrow[r] * f[r] + sm;
        }
#pragma unroll
        for (int j = 0; j < 4; ++j)
#pragma unroll
            for (int r = 0; r < 4; ++r) Oacc[j][r] *= f[r];

        // P (C-layout) -> LDS (swizzled); wave-local stripe, no barrier needed
#pragma unroll
        for (int j = 0; j < 4; ++j) {
            const int col = (lane & 15) + j * 16;
#pragma unroll
            for (int r = 0; r < 4; ++r) {
                const int row = wave * 16 + (lane >> 4) * 4 + r;
                *(unsigned short*)((char*)Ps + row * 128 + ((col * 2) ^ ((row & 7) << 4))) =
                    f2bf(s[j][r]);
            }
        }

#pragma unroll
        for (int ks = 0; ks < 2; ++ks) {
            const int kbase = ks * 64 + (lane >> 4) * 16;
            const int ra = wave * 16 + (lane & 15);
            short8 ap = *(const short8*)((const char*)Ps + ra * 128 + (kbase ^ ((ra & 7) << 4)));
#pragma unroll
            for (int j = 0; j < 4; ++j) {
                const int rb = j * 16 + (lane & 15);
                short8 bv8 = *(const short8*)((const char*)Vc + rb * 128 + (kbase ^ ((rb & 7) << 4)));
                Oacc[j] = __builtin_amdgcn_mfma_f32_16x16x32_bf16(ap, bv8, Oacc[j], 0, 0, 0);
            }
        }
        __syncthreads();
    }

    float* Oz = Of + (size_t)z * 524288;
#pragma unroll
    for (int j = 0; j < 4; ++j) {
        const int c = h * 64 + j * 16 + (lane & 15);
#pragma unroll
        for (int r = 0; r < 4; ++r) {
            const int row = q0 + wave * 16 + (lane >> 4) * 4 + r;
            Oz[(size_t)row * D_ + c] = Oacc[j][r];
        }
    }
    if ((lane & 15) == 0) {
#pragma unroll
        for (int r = 0; r < 4; ++r) {
            const int row = q0 + wave * 16 + (lane >> 4) * 4 + r;
            float* dst = mlb + (((size_t)z * NH + h) * 1024 + row) * 2;
            dst[0] = mrow[r];
            dst[1] = lrow[r];
        }
    }
}

// ---------------------------------------------------------------------------
// Merge the two KV-split partials (per head-row m,l).
// ---------------------------------------------------------------------------
__global__ __launch_bounds__(256) void flash_merge(
    const float* __restrict__ Of, const float* __restrict__ mlb,
    unsigned short* __restrict__ O)
{
    const int tid = threadIdx.x;
    const int row = blockIdx.x * 4 + (tid >> 6);
    const int lane = tid & 63;
    const int d0 = lane * 8;
    const int h = d0 >> 6;
    const float* ml0 = mlb + (((size_t)0 * NH + h) * 1024 + row) * 2;
    const float* ml1 = mlb + (((size_t)1 * NH + h) * 1024 + row) * 2;
    const float m0 = ml0[0], l0 = ml0[1], m1 = ml1[0], l1 = ml1[1];
    const float m = fmaxf(m0, m1);
    const float a0 = expf(m0 - m), a1 = expf(m1 - m);
    const float inv = 1.0f / (a0 * l0 + a1 * l1);
    const float* p0 = Of + (size_t)row * D_ + d0;
    const float* p1 = Of + 524288 + (size_t)row * D_ + d0;
    float4 x0 = *(const float4*)p0, x1 = *(const float4*)(p0 + 4);
    float4 y0 = *(const float4*)p1, y1 = *(const float4*)(p1 + 4);
    ushort4 o0, o1;
    o0.x = f2bf((a0 * x0.x + a1 * y0.x) * inv);
    o0.y = f2bf((a0 * x0.y + a1 * y0.y) * inv);
    o0.z = f2bf((a0 * x0.z + a1 * y0.z) * inv);
    o0.w = f2bf((a0 * x0.w + a1 * y0.w) * inv);
    o1.x = f2bf((a0 * x1.x + a1 * y1.x) * inv);
    o1.y = f2bf((a0 * x1.y + a1 * y1.y) * inv);
    o1.z = f2bf((a0 * x1.z + a1 * y1.z) * inv);
    o1.w = f2bf((a0 * x1.w + a1 * y1.w) * inv);
    *(ushort4*)(O + (size_t)row * D_ + d0) = o0;
    *(ushort4*)(O + (size_t)row * D_ + d0 + 4) = o1;
}

// ---------------------------------------------------------------------------
// LN over y = x(resid) + bias + sum of NZ split-K partials. One wave per row.
// ---------------------------------------------------------------------------
template<int NZ>
__global__ __launch_bounds__(64) void ln_sum_kernel(
    const float* __restrict__ y4,     // [NZ][1024][512]
    const float* __restrict__ bias,   // [512]
    const float* __restrict__ w, const float* __restrict__ b,
    float* __restrict__ x, unsigned short* __restrict__ xb)
{
    const int row = blockIdx.x;
    const int lane = threadIdx.x;
    const size_t off = (size_t)row * 512 + lane * 8;
    float vals[8];
#pragma unroll
    for (int j = 0; j < 8; ++j) vals[j] = x[off + j] + bias[lane * 8 + j];
#pragma unroll
    for (int z = 0; z < NZ; ++z) {
        float4 p0 = *(const float4*)(y4 + (size_t)z * 524288 + off);
        float4 p1 = *(const float4*)(y4 + (size_t)z * 524288 + off + 4);
        vals[0] += p0.x; vals[1] += p0.y; vals[2] += p0.z; vals[3] += p0.w;
        vals[4] += p1.x; vals[5] += p1.y; vals[6] += p1.z; vals[7] += p1.w;
    }
    float s = 0.f;
#pragma unroll
    for (int j = 0; j < 8; ++j) s += vals[j];
#pragma unroll
    for (int o = 32; o >= 1; o >>= 1) s += __shfl_xor(s, o);
    const float mu = s * (1.f / 512.f);
    float q = 0.f;
#pragma unroll
    for (int j = 0; j < 8; ++j) { float d = vals[j] - mu; q += d * d; }
#pragma unroll
    for (int o = 32; o >= 1; o >>= 1) q += __shfl_xor(q, o);
    const float inv = 1.0f / sqrtf(q * (1.f / 512.f) + EPS_);
    float ov[8];
#pragma unroll
    for (int j = 0; j < 8; ++j)
        ov[j] = (vals[j] - mu) * inv * w[lane * 8 + j] + b[lane * 8 + j];
    float4 o0 = {ov[0], ov[1], ov[2], ov[3]};
    float4 o1 = {ov[4], ov[5], ov[6], ov[7]};
    *(float4*)(x + off) = o0;
    *(float4*)(x + off + 4) = o1;
    ushort4 u0, u1;
    u0.x = f2bf(ov[0]); u0.y = f2bf(ov[1]); u0.z = f2bf(ov[2]); u0.w = f2bf(ov[3]);
    u1.x = f2bf(ov[4]); u1.y = f2bf(ov[5]); u1.z = f2bf(ov[6]); u1.w = f2bf(ov[7]);
    *(ushort4*)(xb + off) = u0;
    *(ushort4*)(xb + off + 4) = u1;
}

// ---------------------------------------------------------------------------
// Fused values+scatter: compute only the 2048 selected (r,c) dot products.
// ---------------------------------------------------------------------------
__global__ __launch_bounds__(256) void scatter_dot(
    const int* __restrict__ rows, const int* __restrict__ cols,
    const unsigned short* __restrict__ xb, __hip_bfloat16* __restrict__ out)
{
    const int k = blockIdx.x * 4 + (threadIdx.x >> 6);
    const int lane = threadIdx.x & 63;
    const int r = rows[k], c = cols[k];
    const unsigned short* xr = xb + (size_t)r * 512 + lane * 8;
    const unsigned short* xc = xb + (size_t)c * 512 + lane * 8;
    ushort4 a0 = *(const ushort4*)xr, a1 = *(const ushort4*)(xr + 4);
    ushort4 b0 = *(const ushort4*)xc, b1 = *(const ushort4*)(xc + 4);
    float s = bf2f(a0.x) * bf2f(b0.x) + bf2f(a0.y) * bf2f(b0.y) +
              bf2f(a0.z) * bf2f(b0.z) + bf2f(a0.w) * bf2f(b0.w) +
              bf2f(a1.x) * bf2f(b1.x) + bf2f(a1.y) * bf2f(b1.y) +
              bf2f(a1.z) * bf2f(b1.z) + bf2f(a1.w) * bf2f(b1.w);
#pragma unroll
    for (int o = 32; o >= 1; o >>= 1) s += __shfl_xor(s, o);
    if (lane == 0) {
        if (!(fabsf(s) < 1e30f)) s = 0.f;
        out[(size_t)r * 1024 + c] = __float2bfloat16(s);
    }
}

// ---------------------------------------------------------------------------
extern "C" void kernel_launch(void* const* d_in, const int* in_sizes, int n_in,
                              void* d_out, int out_size, void* d_ws, size_t ws_size,
                              hipStream_t stream)
{
    const float* ideal  = (const float*)d_in[0];
    const int*   rows   = (const int*)d_in[1];
    const int*   cols   = (const int*)d_in[2];
    const float* Wm     = (const float*)d_in[3];
    const float* bm     = (const float*)d_in[4];
    const float* Wphi1  = (const float*)d_in[5];
    const float* bphi1  = (const float*)d_in[6];
    const float* Wphi2  = (const float*)d_in[7];
    const float* bphi2  = (const float*)d_in[8];
    const float* Wrho1  = (const float*)d_in[9];
    const float* brho1  = (const float*)d_in[10];
    const float* Wrho2  = (const float*)d_in[11];
    const float* brho2  = (const float*)d_in[12];
    const float* Wq     = (const float*)d_in[13];
    const float* bq     = (const float*)d_in[14];
    const float* Wk     = (const float*)d_in[15];
    const float* bk     = (const float*)d_in[16];
    const float* Wv     = (const float*)d_in[17];
    const float* bv     = (const float*)d_in[18];
    const float* Wo     = (const float*)d_in[19];
    const float* bo     = (const float*)d_in[20];
    const float* ln1w   = (const float*)d_in[21];
    const float* ln1b   = (const float*)d_in[22];
    const float* W1     = (const float*)d_in[23];
    const float* b1     = (const float*)d_in[24];
    const float* W2     = (const float*)d_in[25];
    const float* b2     = (const float*)d_in[26];
    const float* ln2w   = (const float*)d_in[27];
    const float* ln2b   = (const float*)d_in[28];
    __hip_bfloat16* out = (__hip_bfloat16*)d_out;

    // ---- Workspace (MB offsets; ws_size = 256 MiB, round-6 evidence) ----
    char* base = (char*)d_ws;
    unsigned short* w_phi1 = (unsigned short*)(base + (0ll  << 20));
    unsigned short* w_phi2 = (unsigned short*)(base + (1ll  << 20));
    unsigned short* w_rho1 = (unsigned short*)(base + (3ll  << 20));
    unsigned short* w_rho2 = (unsigned short*)(base + (5ll  << 20));
    unsigned short* w_qkv  = (unsigned short*)(base + (6ll  << 20));
    unsigned short* w_o    = (unsigned short*)(base + (12ll << 20));
    unsigned short* w_1    = (unsigned short*)(base + (14ll << 20));
    unsigned short* w_2    = (unsigned short*)(base + (22ll << 20));
    float*          b_qkvc = (float*)         (base + (30ll << 20));
    unsigned short* h0b    = (unsigned short*)(base + (31ll << 20));  // 64MB
    unsigned short* h1b    = (unsigned short*)(base + (95ll << 20));  // 128MB
    float*          sbuf   = (float*)         (base + (223ll << 20)); // 4MB
    unsigned short* id_pad = (unsigned short*)(base + (227ll << 20)); // 8MB
    unsigned short* wm_pad = (unsigned short*)(base + (236ll << 20)); // 64KB
    unsigned short* sb_b   = (unsigned short*)(base + (31ll << 20));
    unsigned short* tb_b   = (unsigned short*)(base + (33ll << 20));
    float*          xbuf   = (float*)         (base + (35ll << 20));
    unsigned short* xb     = (unsigned short*)(base + (37ll << 20));
    unsigned short* qkvb   = (unsigned short*)(base + (40ll << 20));
    unsigned short* vT     = (unsigned short*)(base + (43ll << 20));
    unsigned short* ob     = (unsigned short*)(base + (44ll << 20));
    unsigned short* ffnt   = (unsigned short*)(base + (45ll << 20));  // 4MB
    float*          ysplit = (float*)         (base + (49ll << 20));  // 8MB
    float*          Of     = (float*)         (base + (57ll << 20));  // 4MB
    float*          mlb    = (float*)         (base + (61ll << 20));  // 128KB

    // ---------------- One mega conversion launch ----------------
    mega_cvt<<<17936, 256, 0, stream>>>(
        Wphi1, Wphi2, Wrho1, Wrho2, Wo, W1, W2,
        w_phi1, w_phi2, w_rho1, w_rho2, w_o, w_1, w_2,
        Wq, Wk, Wv, bq, bk, bv, w_qkv, b_qkvc,
        ideal, id_pad, Wm, wm_pad, (unsigned short*)out);

    // ---------------- DeepSets ----------------
    // embed as K=64 MFMA GEMM
    mfma_nt<128, 128, 0, false, true, true, false, false, false, false, false>
        <<<dim3(4, 512), 256, 0, stream>>>(
        id_pad, 0, 64, wm_pad, 0, 64, bm, nullptr, 0, h0b, 0, D_, 64, 1.0f, nullptr);
    // phi1 (MODE 2, validated single-buffer path)
    mfma_nt<128, 128, 2, false, true, true, false, false, false, false, false>
        <<<4096, 256, 0, stream>>>(
        h0b, 0, D_, w_phi1, 0, D_, bphi1, nullptr, 0, h1b, 0, HID_, D_, 1.0f, nullptr);
    // phi2+pool (MODE 2)
    mfma_nt<128, 128, 2, true, true, true, true, false, false, false, false>
        <<<4096, 256, 0, stream>>>(
        h1b, 0, HID_, w_phi2, 0, HID_, bphi2, nullptr, 0, sbuf, 0, HID_, HID_, 1.0f, nullptr);

    // rho (64^2 tiles, DBUF); rho2 writes BOTH xbuf f32 + xb bf16
    cvt_bf16_kernel<<<1024, 256, 0, stream>>>(sbuf, sb_b, 262144);
    mfma_nt<64, 64, 0, false, true, true, false, false, false, true, false>
        <<<dim3(16, 16), 256, 0, stream>>>(
        sb_b, 0, HID_, w_rho1, 0, HID_, brho1, nullptr, 0, tb_b, 0, HID_, HID_, 1.0f, nullptr);
    mfma_nt<64, 64, 0, true, true, true, false, false, false, true, true>
        <<<dim3(8, 16), 256, 0, stream>>>(
        tb_b, 0, HID_, w_rho2, 0, HID_, brho2, nullptr, 0, xbuf, 0, D_, HID_, 1.0f, xb);

    // ---------------- Transformer ----------------
    for (int l = 0; l < NL; ++l) {
        // QKV fused (TRANSV writes vT for V-region blocks)
        mfma_nt<64, 64, 0, false, true, false, false, false, true, true, false>
            <<<dim3(24, 16), 256, 0, stream>>>(
            xb, 0, D_, w_qkv + (long long)l * 1536 * D_, 0, D_, b_qkvc + l * 1536,
            nullptr, 0, qkvb, 0, 1536, D_, 1.0f, vT);
        // flash attention KV-split-2 + merge
        flash_attn<<<dim3(16, NH, 2), 256, 0, stream>>>(qkvb, vT, Of, mlb);
        flash_merge<<<256, 256, 0, stream>>>(Of, mlb, ob);
        // Wo split-K=2 -> partials; ln_sum<2> folds bias+resid+LN1
        mfma_nt<64, 64, 0, true, false, false, false, false, false, true, false>
            <<<dim3(8, 16, 2), 256, 0, stream>>>(
            ob, 256, D_, w_o + (long long)l * D_ * D_, 256, D_, nullptr,
            nullptr, 0, ysplit, 524288, D_, 256, 1.0f, nullptr);
        ln_sum_kernel<2><<<NP, 64, 0, stream>>>(ysplit, bo + l * D_,
                                                ln1w + l * D_, ln1b + l * D_, xbuf, xb);
        // ffn1: xb @ W1^T + b1, relu -> bf16
        mfma_nt<64, 64, 0, false, true, true, false, false, false, true, false>
            <<<dim3(32, 16), 256, 0, stream>>>(
            xb, 0, D_, w_1 + (long long)l * FF_ * D_, 0, D_, b1 + l * FF_,
            nullptr, 0, ffnt, 0, FF_, D_, 1.0f, nullptr);
        // ffn2 split-K=4 -> partials; ln_sum<4> folds bias+resid+LN2
        mfma_nt<64, 64, 0, true, false, false, false, false, false, true, false>
            <<<dim3(8, 16, 4), 256, 0, stream>>>(
            ffnt, 512, FF_, w_2 + (long long)l * D_ * FF_, 512, FF_, nullptr,
            nullptr, 0, ysplit, 524288, D_, 512, 1.0f, nullptr);
        ln_sum_kernel<4><<<NP, 64, 0, stream>>>(ysplit, b2 + l * D_,
                                                ln2w + l * D_, ln2b + l * D_, xbuf, xb);
    }

    // scatter: out[r,c] = dot(x[r], x[c]) for the 2048 selected pairs only
    scatter_dot<<<NK / 4, 256, 0, stream>>>(rows, cols, xb, out);
}